// Round 3
// baseline (25.854 us; speedup 1.0000x reference)
//
#include <hip/hip_runtime.h>
#include <math.h>

#define BATCH 4
#define NPTS  32
#define IMH   512
#define IMW   512
#define HB    64
#define TPW   64    // tile width  (16 lane-groups x 4 px)
#define TPH   16    // tile height (rows; wave w owns rows 4w..4w+3)

// One fused kernel, uniform waves:
//  - all threads: issue float4 image loads (latency hidden under spline)
//  - all threads: stage 16KB brush alpha -> LDS (float4 loads, scalar ds writes)
//  - each wave:   natural-cubic spline via shuffles (lane k = node k), rcp-mul Thomas
//  - each wave:   exact bbox cull vs its own 64x4 strip, ballot + shfl-broadcast loop
//  - composite 4 px/thread, bilinear from LDS, float4 stores
__global__ __launch_bounds__(256) void fused_paint_kernel(
    const float* __restrict__ images, const float* __restrict__ traj,
    const float* __restrict__ colors, const float* __restrict__ brush,
    float* __restrict__ out) {
  __shared__ float sA[HB][HB + 1];   // brush alpha, padded stride

  int b = blockIdx.z;
  int t = threadIdx.x;
  int lane = t & 63;
  int w = t >> 6;

  int c0 = blockIdx.x * TPW, r0 = blockIdx.y * TPH;
  int col = c0 + (t & 15) * 4;
  int row = r0 + (t >> 4);
  size_t plane = (size_t)IMH * IMW;
  size_t base = (size_t)b * 4 * plane + (size_t)row * IMW + col;

  // Issue image loads early.
  float4 v0 = *(const float4*)(images + base);
  float4 v1 = *(const float4*)(images + base + plane);
  float4 v2 = *(const float4*)(images + base + 2 * plane);
  float4 v3 = *(const float4*)(images + base + 3 * plane);
  float cr = colors[b * 4 + 0], cg = colors[b * 4 + 1];
  float cb = colors[b * 4 + 2], ca = colors[b * 4 + 3];

  // ---- cooperative brush staging (all 256 threads, float4 global loads) ----
  const float* bA = brush + 3 * HB * HB;
  #pragma unroll
  for (int it = 0; it < 4; ++it) {
    int idx = t * 4 + it * 1024;          // 4-aligned, never crosses a row of 64
    float4 a4 = *(const float4*)(bA + idx);
    int r = idx >> 6, c = idx & 63;
    sA[r][c]     = a4.x;
    sA[r][c + 1] = a4.y;
    sA[r][c + 2] = a4.z;
    sA[r][c + 3] = a4.w;
  }

  // ---- per-wave spline (lane k = node k); overlaps image-load drain ----
  const float* tb = traj + b * 4 * NPTS;
  float tsv = 0.f, xv = 0.f, yv = 0.f, zv = 0.f;
  if (lane < NPTS) {
    tsv = tb[0 * NPTS + lane];
    xv  = tb[1 * NPTS + lane];
    yv  = tb[2 * NPTS + lane];
    zv  = tb[3 * NPTS + lane];
  }
  float ts1 = __shfl_down(tsv, 1);
  float x1  = __shfl_down(xv, 1);
  float y1  = __shfl_down(yv, 1);
  float hv  = ts1 - tsv;
  float rhv = 1.0f / hv;
  float sxv = (x1 - xv) * rhv;
  float syv = (y1 - yv) * rhv;

  // Thomas forward sweep, interior i = 1..30 (M[0]=M[31]=0); rcp-mul form.
  float cpv = 0.f, ddx = 0.f, ddy = 0.f;
  float cp_prev = 0.f, dx_prev = 0.f, dy_prev = 0.f;
  #pragma unroll 1
  for (int i = 1; i <= NPTS - 2; ++i) {
    float a  = __shfl(hv, i - 1);
    float hi = __shfl(hv, i);
    float rx = 6.0f * (__shfl(sxv, i) - __shfl(sxv, i - 1));
    float ry = 6.0f * (__shfl(syv, i) - __shfl(syv, i - 1));
    float m  = 2.0f * (a + hi) - a * cp_prev;
    float im = 1.0f / m;
    float cpi = hi * im;
    float dxi = (rx - a * dx_prev) * im;
    float dyi = (ry - a * dy_prev) * im;
    if (lane == i) { cpv = cpi; ddx = dxi; ddy = dyi; }
    cp_prev = cpi; dx_prev = dxi; dy_prev = dyi;
  }
  // Back substitution.
  float Mxv = 0.f, Myv = 0.f;
  float mx_next = 0.f, my_next = 0.f;
  #pragma unroll 1
  for (int i = NPTS - 2; i >= 1; --i) {
    float cpi = __shfl(cpv, i);
    float dxi = __shfl(ddx, i);
    float dyi = __shfl(ddy, i);
    float mxi = dxi - cpi * mx_next;
    float myi = dyi - cpi * my_next;
    if (lane == i) { Mxv = mxi; Myv = myi; }
    mx_next = mxi; my_next = myi;
  }
  // Node derivatives (uniform shuffles before divergence).
  float Mx1  = __shfl_down(Mxv, 1);
  float My1  = __shfl_down(Myv, 1);
  float sx30 = __shfl(sxv, NPTS - 2);
  float sy30 = __shfl(syv, NPTS - 2);
  float h30  = __shfl(hv,  NPTS - 2);
  float Mx30 = __shfl(Mxv, NPTS - 2);
  float My30 = __shfl(Myv, NPTS - 2);
  float Mx31 = __shfl(Mxv, NPTS - 1);
  float My31 = __shfl(Myv, NPTS - 1);

  float dX, dY;
  if (lane < NPTS - 1) {
    dX = sxv - hv * (2.0f * Mxv + Mx1) / 6.0f;
    dY = syv - hv * (2.0f * Myv + My1) / 6.0f;
  } else {
    dX = sx30 + h30 * (2.0f * Mx31 + Mx30) / 6.0f;
    dY = sy30 + h30 * (2.0f * My31 + My30) / 6.0f;
  }

  // Per-stroke pose + per-wave strip cull.
  float cthv = 1.f, sthv = 0.f, iscv = 1.f;
  bool pred = false;
  {
    float r2 = dX * dX + dY * dY;
    if (r2 > 0.f) { float inv = 1.0f / sqrtf(r2); cthv = dX * inv; sthv = -dY * inv; }
    float scale = fminf(fmaxf(zv, 0.001f), 1.0f);
    iscv = 1.0f / scale;
    // Exact support: alpha>0 only within sprite-dist 32; bilinear reach +sqrt(2)
    // -> image-space radius 33.42*scale. 33.6+0.5 is conservative.
    float R = scale * 33.6f + 0.5f;
    float sx0 = (float)c0, sx1 = (float)(c0 + TPW - 1);
    float sy0 = (float)(r0 + w * 4), sy1 = sy0 + 3.f;
    pred = (lane < NPTS) && (zv > 0.f) &&
           (xv + R >= sx0) && (xv - R <= sx1) &&
           (yv + R >= sy0) && (yv - R <= sy1);
  }
  unsigned long long mask = __ballot(pred);

  __syncthreads();   // brush staging complete (symmetric waves, minimal skew)

  float gr[4], gg[4], gb[4];
  gr[0] = 1.f - v0.x; gr[1] = 1.f - v0.y; gr[2] = 1.f - v0.z; gr[3] = 1.f - v0.w;
  gg[0] = 1.f - v1.x; gg[1] = 1.f - v1.y; gg[2] = 1.f - v1.z; gg[3] = 1.f - v1.w;
  gb[0] = 1.f - v2.x; gb[1] = 1.f - v2.y; gb[2] = 1.f - v2.z; gb[3] = 1.f - v2.w;

  float fry = (float)row;

  // Iterate surviving strokes in k-order (low bit -> high bit), broadcast params.
  while (mask) {
    int src = __builtin_ctzll(mask);
    mask &= mask - 1;
    float px  = __shfl(xv, src), py  = __shfl(yv, src);
    float cth = __shfl(cthv, src), sth = __shfl(sthv, src), isc = __shfl(iscv, src);
    float dy = fry - py;
    float lxb = (cth * ((float)col - px) - sth * dy) * isc + 0.5f * (HB - 1);
    float lyb = (sth * ((float)col - px) + cth * dy) * isc + 0.5f * (HB - 1);
    float cdx = cth * isc, sdx = sth * isc;   // d(lx)/d(col), d(ly)/d(col)
    #pragma unroll
    for (int i = 0; i < 4; ++i) {
      float lx = lxb + cdx * (float)i;
      float ly = lyb + sdx * (float)i;
      if (lx <= -1.f || lx >= (float)HB || ly <= -1.f || ly >= (float)HB) continue;
      float x0f = floorf(lx), y0f = floorf(ly);
      float wx = lx - x0f, wy = ly - y0f;
      int x0 = (int)x0f, y0 = (int)y0f;
      int x1i = x0 + 1, y1i = y0 + 1;
      bool xv0 = (x0  >= 0) && (x0  < HB);
      bool xv1 = (x1i >= 0) && (x1i < HB);
      bool yv0 = (y0  >= 0) && (y0  < HB);
      bool yv1 = (y1i >= 0) && (y1i < HB);
      int xc0 = min(max(x0,  0), HB - 1);
      int xc1 = min(max(x1i, 0), HB - 1);
      int yc0 = min(max(y0,  0), HB - 1);
      int yc1 = min(max(y1i, 0), HB - 1);
      float f00 = (xv0 && yv0) ? 1.f : 0.f;
      float f01 = (xv1 && yv0) ? 1.f : 0.f;
      float f10 = (xv0 && yv1) ? 1.f : 0.f;
      float f11 = (xv1 && yv1) ? 1.f : 0.f;
      float v00 = sA[yc0][xc0] * f00;
      float v01 = sA[yc0][xc1] * f01;
      float v10 = sA[yc1][xc0] * f10;
      float v11 = sA[yc1][xc1] * f11;
      float w00 = (1.f - wx) * (1.f - wy);
      float w01 = wx * (1.f - wy);
      float w10 = (1.f - wx) * wy;
      float w11 = wx * wy;
      float asamp = v00 * w00 + v01 * w01 + v10 * w10 + v11 * w11;
      float aa    = ca * asamp;                                      // sprite alpha
      float wsum  = f00 * w00 + f01 * w01 + f10 * w10 + f11 * w11;   // rgb coverage
      float om = 1.f - aa;
      gr[i] = gr[i] * om + (1.f - cr * wsum) * aa;
      gg[i] = gg[i] * om + (1.f - cg * wsum) * aa;
      gb[i] = gb[i] * om + (1.f - cb * wsum) * aa;
    }
  }

  float4 o0 = make_float4(1.f - gr[0], 1.f - gr[1], 1.f - gr[2], 1.f - gr[3]);
  float4 o1 = make_float4(1.f - gg[0], 1.f - gg[1], 1.f - gg[2], 1.f - gg[3]);
  float4 o2 = make_float4(1.f - gb[0], 1.f - gb[1], 1.f - gb[2], 1.f - gb[3]);
  *(float4*)(out + base)             = o0;
  *(float4*)(out + base + plane)     = o1;
  *(float4*)(out + base + 2 * plane) = o2;
  *(float4*)(out + base + 3 * plane) = v3;
}

extern "C" void kernel_launch(void* const* d_in, const int* in_sizes, int n_in,
                              void* d_out, int out_size, void* d_ws, size_t ws_size,
                              hipStream_t stream) {
  const float* images = (const float*)d_in[0];   // (B,4,H,W) f32
  const float* traj   = (const float*)d_in[1];   // (B,4,N)   f32
  const float* colors = (const float*)d_in[2];   // (B,4)     f32
  const float* brush  = (const float*)d_in[3];   // (4,HB,HB) f32
  float* outp = (float*)d_out;                   // (B,4,H,W) f32

  fused_paint_kernel<<<dim3(IMW / TPW, IMH / TPH, BATCH), 256, 0, stream>>>(
      images, traj, colors, brush, outp);
}

// Round 4
// 21.442 us; speedup vs baseline: 1.2058x; 1.2058x over previous
//
#include <hip/hip_runtime.h>
#include <math.h>

#define BATCH 4
#define NPTS  32
#define IMH   512
#define IMW   512
#define HB    64
#define TPW   128   // tile width  (32 lanes x 4 px)
#define TPH   8     // tile height (8 rows; wave w owns rows 2w, 2w+1)

// ---------------- Kernel 1: natural cubic spline -> per-stroke params ----------------
// One block (1 wave) per batch. Lane k (k<32) holds node k. Thomas algorithm via shuffles.
// params[(b*NPTS+k)*8 + {0..7}] = {x, y, cos(th), sin(th), 1/scale, cull_radius, active, pad}
__global__ __launch_bounds__(64) void spline_kernel(
    const float* __restrict__ traj, float* __restrict__ params) {
  int b = blockIdx.x;
  int lane = threadIdx.x;
  const float* tb = traj + b * 4 * NPTS;
  float tsv = 0.f, xv = 0.f, yv = 0.f, zv = 0.f;
  if (lane < NPTS) {
    tsv = tb[0 * NPTS + lane];
    xv  = tb[1 * NPTS + lane];
    yv  = tb[2 * NPTS + lane];
    zv  = tb[3 * NPTS + lane];
  }
  float ts1 = __shfl_down(tsv, 1);
  float x1  = __shfl_down(xv, 1);
  float y1  = __shfl_down(yv, 1);
  float hv  = ts1 - tsv;
  float sxv = (x1 - xv) / hv;
  float syv = (y1 - yv) / hv;

  // Thomas forward sweep over interior unknowns i = 1..30 (M[0]=M[31]=0).
  float cpv = 0.f, ddx = 0.f, ddy = 0.f;
  float cp_prev = 0.f, dx_prev = 0.f, dy_prev = 0.f;
  for (int i = 1; i <= NPTS - 2; ++i) {
    float a  = __shfl(hv, i - 1);
    float hi = __shfl(hv, i);
    float rx = 6.0f * (__shfl(sxv, i) - __shfl(sxv, i - 1));
    float ry = 6.0f * (__shfl(syv, i) - __shfl(syv, i - 1));
    float bb = 2.0f * (a + hi);
    float m  = bb - a * cp_prev;
    float cpi = hi / m;
    float dxi = (rx - a * dx_prev) / m;
    float dyi = (ry - a * dy_prev) / m;
    if (lane == i) { cpv = cpi; ddx = dxi; ddy = dyi; }
    cp_prev = cpi; dx_prev = dxi; dy_prev = dyi;
  }
  // Back substitution: lane i keeps M[i].
  float Mxv = 0.f, Myv = 0.f;
  float mx_next = 0.f, my_next = 0.f;
  for (int i = NPTS - 2; i >= 1; --i) {
    float cpi = __shfl(cpv, i);
    float dxi = __shfl(ddx, i);
    float dyi = __shfl(ddy, i);
    float mxi = dxi - cpi * mx_next;
    float myi = dyi - cpi * my_next;
    if (lane == i) { Mxv = mxi; Myv = myi; }
    mx_next = mxi; my_next = myi;
  }
  // Node derivatives (uniform shuffles before divergence).
  float Mx1  = __shfl_down(Mxv, 1);
  float My1  = __shfl_down(Myv, 1);
  float sx30 = __shfl(sxv, NPTS - 2);
  float sy30 = __shfl(syv, NPTS - 2);
  float h30  = __shfl(hv,  NPTS - 2);
  float Mx30 = __shfl(Mxv, NPTS - 2);
  float My30 = __shfl(Myv, NPTS - 2);
  float Mx31 = __shfl(Mxv, NPTS - 1);
  float My31 = __shfl(Myv, NPTS - 1);

  float dX, dY;
  if (lane < NPTS - 1) {
    dX = sxv - hv * (2.0f * Mxv + Mx1) / 6.0f;
    dY = syv - hv * (2.0f * Myv + My1) / 6.0f;
  } else {
    dX = sx30 + h30 * (2.0f * Mx31 + Mx30) / 6.0f;
    dY = sy30 + h30 * (2.0f * My31 + My30) / 6.0f;
  }
  if (lane < NPTS) {
    float r2 = dX * dX + dY * dY;
    float c, s;
    if (r2 > 0.f) { float inv = 1.0f / sqrtf(r2); c = dX * inv; s = -dY * inv; }
    else          { c = 1.f; s = 0.f; }
    float scale = fminf(fmaxf(zv, 0.001f), 1.0f);
    float* p = params + (b * NPTS + lane) * 8;
    p[0] = xv;
    p[1] = yv;
    p[2] = c;
    p[3] = s;
    p[4] = 1.0f / scale;
    // Exact support radius is 33.42*scale (alpha>0 disc 32 + bilinear sqrt(2)).
    p[5] = scale * 33.6f + 0.5f;
    p[6] = (zv > 0.f) ? 1.f : 0.f;
    p[7] = 0.f;
  }
}

// ---------------- Kernel 2: streaming composite, no LDS, no barrier ----------------
__global__ __launch_bounds__(256) void paint_kernel(
    const float* __restrict__ images, const float* __restrict__ params,
    const float* __restrict__ colors, const float* __restrict__ brush,
    float* __restrict__ out) {
  int b = blockIdx.z;
  int t = threadIdx.x;
  int lane = t & 63;
  int w = t >> 6;
  int tx = t & 31, ty = t >> 5;
  int c0 = blockIdx.x * TPW, r0 = blockIdx.y * TPH;
  int col = c0 + tx * 4, row = r0 + ty;
  size_t plane = (size_t)IMH * IMW;
  size_t base = (size_t)b * 4 * plane + (size_t)row * IMW + col;

  // Streaming loads first (fill HBM latency under cull).
  float4 v0 = *(const float4*)(images + base);
  float4 v1 = *(const float4*)(images + base + plane);
  float4 v2 = *(const float4*)(images + base + 2 * plane);
  float4 v3 = *(const float4*)(images + base + 3 * plane);
  // Uniform (scalarized) color loads.
  float cr = colors[b * 4 + 0], cg = colors[b * 4 + 1];
  float cb = colors[b * 4 + 2], ca = colors[b * 4 + 3];

  // Lane k holds stroke k's params; cull vs this wave's 128x2 strip.
  float px = 0.f, py = 0.f, cthv = 1.f, sthv = 0.f, iscv = 1.f;
  bool pred = false;
  if (lane < NPTS) {
    const float4* pp = (const float4*)(params + ((size_t)b * NPTS + lane) * 8);
    float4 p0 = pp[0];
    float4 p1 = pp[1];
    px = p0.x; py = p0.y; cthv = p0.z; sthv = p0.w; iscv = p1.x;
    float R = p1.y;
    float sx0 = (float)c0, sx1 = (float)(c0 + TPW - 1);
    float sy0 = (float)(r0 + w * 2), sy1 = sy0 + 1.f;
    pred = (p1.z > 0.f) &&
           (px + R >= sx0) && (px - R <= sx1) &&
           (py + R >= sy0) && (py - R <= sy1);
  }
  unsigned long long mask = __ballot(pred);

  float gr[4], gg[4], gb[4];
  gr[0] = 1.f - v0.x; gr[1] = 1.f - v0.y; gr[2] = 1.f - v0.z; gr[3] = 1.f - v0.w;
  gg[0] = 1.f - v1.x; gg[1] = 1.f - v1.y; gg[2] = 1.f - v1.z; gg[3] = 1.f - v1.w;
  gb[0] = 1.f - v2.x; gb[1] = 1.f - v2.y; gb[2] = 1.f - v2.z; gb[3] = 1.f - v2.w;

  const float* bA = brush + 3 * HB * HB;   // alpha plane, 16KB -> L1-resident
  float fry = (float)row;

  // Iterate surviving strokes in ascending k (compositing order exact).
  while (mask) {
    int src = __builtin_ctzll(mask);
    mask &= mask - 1;
    float spx = __shfl(px, src), spy = __shfl(py, src);
    float cth = __shfl(cthv, src), sth = __shfl(sthv, src), isc = __shfl(iscv, src);
    float dy = fry - spy;
    float dx0 = (float)col - spx;
    float lxb = (cth * dx0 - sth * dy) * isc + 0.5f * (HB - 1);
    float lyb = (sth * dx0 + cth * dy) * isc + 0.5f * (HB - 1);
    float cdx = cth * isc, sdx = sth * isc;
    #pragma unroll
    for (int i = 0; i < 4; ++i) {
      float lx = lxb + cdx * (float)i;
      float ly = lyb + sdx * (float)i;
      if (lx <= -1.f || lx >= (float)HB || ly <= -1.f || ly >= (float)HB) continue;
      float x0f = floorf(lx), y0f = floorf(ly);
      float wx = lx - x0f, wy = ly - y0f;
      int x0 = (int)x0f, y0 = (int)y0f;
      int x1i = x0 + 1, y1i = y0 + 1;
      bool xv0 = (x0  >= 0) && (x0  < HB);
      bool xv1 = (x1i >= 0) && (x1i < HB);
      bool yv0 = (y0  >= 0) && (y0  < HB);
      bool yv1 = (y1i >= 0) && (y1i < HB);
      int xc0 = min(max(x0,  0), HB - 1);
      int xc1 = min(max(x1i, 0), HB - 1);
      int yc0 = min(max(y0,  0), HB - 1);
      int yc1 = min(max(y1i, 0), HB - 1);
      float f00 = (xv0 && yv0) ? 1.f : 0.f;
      float f01 = (xv1 && yv0) ? 1.f : 0.f;
      float f10 = (xv0 && yv1) ? 1.f : 0.f;
      float f11 = (xv1 && yv1) ? 1.f : 0.f;
      float v00 = bA[yc0 * HB + xc0] * f00;
      float v01 = bA[yc0 * HB + xc1] * f01;
      float v10 = bA[yc1 * HB + xc0] * f10;
      float v11 = bA[yc1 * HB + xc1] * f11;
      float w00 = (1.f - wx) * (1.f - wy);
      float w01 = wx * (1.f - wy);
      float w10 = (1.f - wx) * wy;
      float w11 = wx * wy;
      float asamp = v00 * w00 + v01 * w01 + v10 * w10 + v11 * w11;
      float aa    = ca * asamp;                                      // sprite alpha
      float wsum  = f00 * w00 + f01 * w01 + f10 * w10 + f11 * w11;   // rgb coverage
      float om = 1.f - aa;
      gr[i] = gr[i] * om + (1.f - cr * wsum) * aa;
      gg[i] = gg[i] * om + (1.f - cg * wsum) * aa;
      gb[i] = gb[i] * om + (1.f - cb * wsum) * aa;
    }
  }

  float4 o0 = make_float4(1.f - gr[0], 1.f - gr[1], 1.f - gr[2], 1.f - gr[3]);
  float4 o1 = make_float4(1.f - gg[0], 1.f - gg[1], 1.f - gg[2], 1.f - gg[3]);
  float4 o2 = make_float4(1.f - gb[0], 1.f - gb[1], 1.f - gb[2], 1.f - gb[3]);
  *(float4*)(out + base)             = o0;
  *(float4*)(out + base + plane)     = o1;
  *(float4*)(out + base + 2 * plane) = o2;
  *(float4*)(out + base + 3 * plane) = v3;
}

extern "C" void kernel_launch(void* const* d_in, const int* in_sizes, int n_in,
                              void* d_out, int out_size, void* d_ws, size_t ws_size,
                              hipStream_t stream) {
  const float* images = (const float*)d_in[0];   // (B,4,H,W) f32
  const float* traj   = (const float*)d_in[1];   // (B,4,N)   f32
  const float* colors = (const float*)d_in[2];   // (B,4)     f32
  const float* brush  = (const float*)d_in[3];   // (4,HB,HB) f32
  float* outp   = (float*)d_out;                 // (B,4,H,W) f32
  float* params = (float*)d_ws;                  // B*N*8 floats scratch

  spline_kernel<<<BATCH, 64, 0, stream>>>(traj, params);
  paint_kernel<<<dim3(IMW / TPW, IMH / TPH, BATCH), 256, 0, stream>>>(
      images, params, colors, brush, outp);
}

// Round 5
// 16.309 us; speedup vs baseline: 1.5853x; 1.3147x over previous
//
#include <hip/hip_runtime.h>
#include <math.h>

#define BATCH 4
#define NPTS  32
#define IMH   512
#define IMW   512
#define HB    64
#define TPW   128   // tile width  (32 lanes x 4 px)
#define TPH   8     // tile height (8 rows; wave w owns rows 2w, 2w+1)

// Single fused kernel, zero barriers, zero LDS.
// Every wave solves the 32-node natural-cubic tridiagonal system itself via
// PCR (parallel cyclic reduction, 5 steps, lane k = row k) — ~60 serial-depth
// instructions instead of Thomas's ~900 — overlapped with in-flight image loads.
// Then per-wave strip cull (ballot) and ctz-ordered composite (order exact).
__global__ __launch_bounds__(256) void fused_paint_kernel(
    const float* __restrict__ images, const float* __restrict__ traj,
    const float* __restrict__ colors, const float* __restrict__ brush,
    float* __restrict__ out) {
  int b = blockIdx.z;
  int t = threadIdx.x;
  int lane = t & 63;
  int w = t >> 6;
  int tx = t & 31, ty = t >> 5;
  int c0 = blockIdx.x * TPW, r0 = blockIdx.y * TPH;
  int col = c0 + tx * 4, row = r0 + ty;
  size_t plane = (size_t)IMH * IMW;
  size_t base = (size_t)b * 4 * plane + (size_t)row * IMW + col;

  // Streaming loads first — HBM latency hides under the PCR spline.
  float4 v0 = *(const float4*)(images + base);
  float4 v1 = *(const float4*)(images + base + plane);
  float4 v2 = *(const float4*)(images + base + 2 * plane);
  float4 v3 = *(const float4*)(images + base + 3 * plane);
  float cr = colors[b * 4 + 0], cg = colors[b * 4 + 1];
  float cb = colors[b * 4 + 2], ca = colors[b * 4 + 3];

  // ---- per-wave spline via PCR (lane k = node k, lanes 0..31) ----
  const float* tb = traj + b * 4 * NPTS;
  float tsv = 0.f, xv = 0.f, yv = 0.f, zv = 0.f;
  if (lane < NPTS) {
    tsv = tb[0 * NPTS + lane];
    xv  = tb[1 * NPTS + lane];
    yv  = tb[2 * NPTS + lane];
    zv  = tb[3 * NPTS + lane];
  }
  // h_i = ts[i+1]-ts[i], s_i = (q[i+1]-q[i])/h_i  (valid i<31)
  float ts1 = __shfl_down(tsv, 1);
  float x1  = __shfl_down(xv, 1);
  float y1  = __shfl_down(yv, 1);
  float hv  = ts1 - tsv;
  float sxv = (x1 - xv) / hv;
  float syv = (y1 - yv) / hv;
  // Row i (interior 1..30): a=h_{i-1}, b=2(h_{i-1}+h_i), c=h_i, r=6(s_i-s_{i-1}).
  // Rows 0,31 (and lanes>=32): identity (a=c=0, b=1, r=0) -> stay identity under PCR.
  float am   = __shfl_up(hv, 1);
  float smx  = __shfl_up(sxv, 1);
  float smy  = __shfl_up(syv, 1);
  bool interior = (lane >= 1) && (lane <= NPTS - 2);
  float A_ = interior ? am : 0.f;
  float C_ = interior ? hv : 0.f;
  float B_ = interior ? 2.0f * (am + hv) : 1.f;
  float Rx = interior ? 6.0f * (sxv - smx) : 0.f;
  float Ry = interior ? 6.0f * (syv - smy) : 0.f;

  // PCR: 5 steps, d = 1,2,4,8,16. Clamped indices hit identity rows => exact.
  #pragma unroll
  for (int d = 1; d < NPTS; d <<= 1) {
    int lo = lane - d; lo = lo < 0 ? 0 : lo;
    int hi = lane + d; hi = hi > NPTS - 1 ? NPTS - 1 : hi;
    float a_lo = __shfl(A_, lo), b_lo = __shfl(B_, lo), c_lo = __shfl(C_, lo);
    float rx_lo = __shfl(Rx, lo), ry_lo = __shfl(Ry, lo);
    float a_hi = __shfl(A_, hi), b_hi = __shfl(B_, hi), c_hi = __shfl(C_, hi);
    float rx_hi = __shfl(Rx, hi), ry_hi = __shfl(Ry, hi);
    float alpha = A_ / b_lo;
    float gamma = C_ / b_hi;
    B_ = B_ - alpha * c_lo - gamma * a_hi;
    Rx = Rx - alpha * rx_lo - gamma * rx_hi;
    Ry = Ry - alpha * ry_lo - gamma * ry_hi;
    A_ = -alpha * a_lo;
    C_ = -gamma * c_hi;
  }
  float Mxv = Rx / B_;   // M[0] = M[31] = 0 automatically (identity rows)
  float Myv = Ry / B_;

  // Node derivatives (uniform shuffles before any divergence).
  float Mx1  = __shfl_down(Mxv, 1);
  float My1  = __shfl_down(Myv, 1);
  float sx30 = __shfl(sxv, NPTS - 2);
  float sy30 = __shfl(syv, NPTS - 2);
  float h30  = __shfl(hv,  NPTS - 2);
  float Mx30 = __shfl(Mxv, NPTS - 2);
  float My30 = __shfl(Myv, NPTS - 2);
  float Mx31 = __shfl(Mxv, NPTS - 1);
  float My31 = __shfl(Myv, NPTS - 1);

  float dX, dY;
  if (lane < NPTS - 1) {
    dX = sxv - hv * (2.0f * Mxv + Mx1) / 6.0f;
    dY = syv - hv * (2.0f * Myv + My1) / 6.0f;
  } else {
    dX = sx30 + h30 * (2.0f * Mx31 + Mx30) / 6.0f;
    dY = sy30 + h30 * (2.0f * My31 + My30) / 6.0f;
  }

  // Pose + per-wave strip cull (strip = 128 x 2 rows).
  float cthv = 1.f, sthv = 0.f, iscv = 1.f;
  bool pred = false;
  {
    float r2 = dX * dX + dY * dY;
    if (r2 > 0.f) { float inv = 1.0f / sqrtf(r2); cthv = dX * inv; sthv = -dY * inv; }
    float scale = fminf(fmaxf(zv, 0.001f), 1.0f);
    iscv = 1.0f / scale;
    // Exact support radius: 33.42*scale (alpha>0 disc 32 + bilinear sqrt(2)).
    float R = scale * 33.6f + 0.5f;
    float sx0 = (float)c0, sx1 = (float)(c0 + TPW - 1);
    float sy0 = (float)(r0 + w * 2), sy1 = sy0 + 1.f;
    pred = (lane < NPTS) && (zv > 0.f) &&
           (xv + R >= sx0) && (xv - R <= sx1) &&
           (yv + R >= sy0) && (yv - R <= sy1);
  }
  unsigned long long mask = __ballot(pred);

  float gr[4], gg[4], gb[4];
  gr[0] = 1.f - v0.x; gr[1] = 1.f - v0.y; gr[2] = 1.f - v0.z; gr[3] = 1.f - v0.w;
  gg[0] = 1.f - v1.x; gg[1] = 1.f - v1.y; gg[2] = 1.f - v1.z; gg[3] = 1.f - v1.w;
  gb[0] = 1.f - v2.x; gb[1] = 1.f - v2.y; gb[2] = 1.f - v2.z; gb[3] = 1.f - v2.w;

  const float* bA = brush + 3 * HB * HB;   // alpha plane, 16KB -> L1-resident
  float fry = (float)row;

  // Surviving strokes in ascending k (compositing order exact).
  while (mask) {
    int src = __builtin_ctzll(mask);
    mask &= mask - 1;
    float spx = __shfl(xv, src), spy = __shfl(yv, src);
    float cth = __shfl(cthv, src), sth = __shfl(sthv, src), isc = __shfl(iscv, src);
    float dy = fry - spy;
    float dx0 = (float)col - spx;
    float lxb = (cth * dx0 - sth * dy) * isc + 0.5f * (HB - 1);
    float lyb = (sth * dx0 + cth * dy) * isc + 0.5f * (HB - 1);
    float cdx = cth * isc, sdx = sth * isc;
    #pragma unroll
    for (int i = 0; i < 4; ++i) {
      float lx = lxb + cdx * (float)i;
      float ly = lyb + sdx * (float)i;
      if (lx <= -1.f || lx >= (float)HB || ly <= -1.f || ly >= (float)HB) continue;
      float x0f = floorf(lx), y0f = floorf(ly);
      float wx = lx - x0f, wy = ly - y0f;
      int x0 = (int)x0f, y0 = (int)y0f;
      int x1i = x0 + 1, y1i = y0 + 1;
      bool xv0 = (x0  >= 0) && (x0  < HB);
      bool xv1 = (x1i >= 0) && (x1i < HB);
      bool yv0 = (y0  >= 0) && (y0  < HB);
      bool yv1 = (y1i >= 0) && (y1i < HB);
      int xc0 = min(max(x0,  0), HB - 1);
      int xc1 = min(max(x1i, 0), HB - 1);
      int yc0 = min(max(y0,  0), HB - 1);
      int yc1 = min(max(y1i, 0), HB - 1);
      float f00 = (xv0 && yv0) ? 1.f : 0.f;
      float f01 = (xv1 && yv0) ? 1.f : 0.f;
      float f10 = (xv0 && yv1) ? 1.f : 0.f;
      float f11 = (xv1 && yv1) ? 1.f : 0.f;
      float v00 = bA[yc0 * HB + xc0] * f00;
      float v01 = bA[yc0 * HB + xc1] * f01;
      float v10 = bA[yc1 * HB + xc0] * f10;
      float v11 = bA[yc1 * HB + xc1] * f11;
      float w00 = (1.f - wx) * (1.f - wy);
      float w01 = wx * (1.f - wy);
      float w10 = (1.f - wx) * wy;
      float w11 = wx * wy;
      float asamp = v00 * w00 + v01 * w01 + v10 * w10 + v11 * w11;
      float aa    = ca * asamp;                                      // sprite alpha
      float wsum  = f00 * w00 + f01 * w01 + f10 * w10 + f11 * w11;   // rgb coverage
      float om = 1.f - aa;
      gr[i] = gr[i] * om + (1.f - cr * wsum) * aa;
      gg[i] = gg[i] * om + (1.f - cg * wsum) * aa;
      gb[i] = gb[i] * om + (1.f - cb * wsum) * aa;
    }
  }

  float4 o0 = make_float4(1.f - gr[0], 1.f - gr[1], 1.f - gr[2], 1.f - gr[3]);
  float4 o1 = make_float4(1.f - gg[0], 1.f - gg[1], 1.f - gg[2], 1.f - gg[3]);
  float4 o2 = make_float4(1.f - gb[0], 1.f - gb[1], 1.f - gb[2], 1.f - gb[3]);
  *(float4*)(out + base)             = o0;
  *(float4*)(out + base + plane)     = o1;
  *(float4*)(out + base + 2 * plane) = o2;
  *(float4*)(out + base + 3 * plane) = v3;
}

extern "C" void kernel_launch(void* const* d_in, const int* in_sizes, int n_in,
                              void* d_out, int out_size, void* d_ws, size_t ws_size,
                              hipStream_t stream) {
  const float* images = (const float*)d_in[0];   // (B,4,H,W) f32
  const float* traj   = (const float*)d_in[1];   // (B,4,N)   f32
  const float* colors = (const float*)d_in[2];   // (B,4)     f32
  const float* brush  = (const float*)d_in[3];   // (4,HB,HB) f32
  float* outp = (float*)d_out;                   // (B,4,H,W) f32

  fused_paint_kernel<<<dim3(IMW / TPW, IMH / TPH, BATCH), 256, 0, stream>>>(
      images, traj, colors, brush, outp);
}